// Round 1
// baseline (138.951 us; speedup 1.0000x reference)
//
#include <hip/hip_runtime.h>
#include <hip/hip_bf16.h>

// SpectralConv1d: out = irfft( pad( einsum('bjix,iox->bjox', rfft(x)[..:64], wr+i*wi) ), n=2048 )
// Decomposed as: GEMM1 (DFT, 16384x128x2048 bf16 MFMA) -> stage2 (complex channel mix, fp32)
//                -> GEMM2 (inverse DFT, 16384x2048x128 bf16 MFMA).

typedef __bf16 bf16x8 __attribute__((ext_vector_type(8)));
typedef float  f32x4  __attribute__((ext_vector_type(4)));

#define SEQ 2048
#define NM2 128   // 2*MODES (Re | Im planes)
#define TWO_PI_OVER_N 3.0679615757712823e-03f

__device__ __forceinline__ unsigned int rnbf(float f) {
  unsigned int u = __builtin_bit_cast(unsigned int, f);
  return (u + 0x7fffu + ((u >> 16) & 1u)) >> 16;  // round-to-nearest-even bf16
}
__device__ __forceinline__ unsigned int pack2(float a, float b) {
  return rnbf(a) | (rnbf(b) << 16);
}

// ---------------- K0: trig tables ----------------
// t1t[c][n], c<64: cos(2*pi*c*n/N); c>=64: -sin(2*pi*(c-64)*n/N)     [128][2048] bf16
// t2t[n][c], c<64: ck*cos;          c>=64: -ck*sin   (ck=1/N or 2/N) [2048][128] bf16
__global__ __launch_bounds__(256) void k_tables(unsigned short* __restrict__ t1t,
                                                unsigned short* __restrict__ t2t) {
  int idx = blockIdx.x * 256 + threadIdx.x;   // 0..262143
  int c = idx >> 11;                          // 0..127
  int n = idx & 2047;
  int k = c & 63;
  float ph = (float)((k * n) & 2047) * TWO_PI_OVER_N;
  float s, co;
  sincosf(ph, &s, &co);
  float v1 = (c < 64) ? co : -s;
  float ck = (k == 0 ? 1.0f : 2.0f) * (1.0f / 2048.0f);
  float v2 = (c < 64) ? ck * co : -ck * s;
  t1t[c * SEQ + n] = (unsigned short)rnbf(v1);
  t2t[n * NM2 + c] = (unsigned short)rnbf(v2);
}

// ---------------- K1: GEMM1  A[16384][128] = x[16384][2048] @ T1 ----------------
// BM=64, BK=64, N=128 full. 4 waves, wave owns 16 rows x 128 cols.
__global__ __launch_bounds__(256) void k_gemm1(const float* __restrict__ x,
                                               const unsigned short* __restrict__ t1t,
                                               float* __restrict__ Aout) {
  __shared__ int4 lds4[(8192 + 16384) / 16];
  char* lds = (char*)lds4;
  const int tid = threadIdx.x;
  const int wave = tid >> 6, lane = tid & 63;
  const int r0 = blockIdx.x * 64;

  f32x4 acc[8] = {};

  const int row_s = tid >> 2;   // staging: 64 rows, 4 threads/row
  const int q_s = tid & 3;
  const float* xrow = x + (r0 + row_s) * SEQ + q_s * 16;
  const unsigned xorA = (unsigned)(row_s & 7) << 4;

  for (int kt = 0; kt < SEQ; kt += 64) {
    __syncthreads();
    // stage x (fp32 -> bf16, swizzled)
    f32x4 f[4];
#pragma unroll
    for (int m = 0; m < 4; ++m) f[m] = *(const f32x4*)(xrow + kt + m * 4);
    unsigned pk[8];
#pragma unroll
    for (int m = 0; m < 4; ++m) {
      pk[2 * m]     = pack2(f[m][0], f[m][1]);
      pk[2 * m + 1] = pack2(f[m][2], f[m][3]);
    }
    uint4 w0; w0.x = pk[0]; w0.y = pk[1]; w0.z = pk[2]; w0.w = pk[3];
    uint4 w1; w1.x = pk[4]; w1.y = pk[5]; w1.z = pk[6]; w1.w = pk[7];
    *(uint4*)(lds + ((row_s * 128 + q_s * 32) ^ xorA))      = w0;
    *(uint4*)(lds + ((row_s * 128 + q_s * 32 + 16) ^ xorA)) = w1;
    // stage T1T tile [128 cols][64 samples] (bf16, swizzled)
#pragma unroll
    for (int p = 0; p < 4; ++p) {
      int seg = tid + 256 * p;          // 0..1023
      int c = seg >> 3, part = seg & 7;
      int4 v = *(const int4*)(t1t + c * SEQ + kt + part * 8);
      *(int4*)(lds + 8192 + ((c * 128 + part * 16) ^ ((unsigned)(c & 7) << 4))) = v;
    }
    __syncthreads();
    // compute
#pragma unroll
    for (int ks = 0; ks < 2; ++ks) {
      const int arow = wave * 16 + (lane & 15);
      const bf16x8 av = *(const bf16x8*)(lds +
          ((arow * 128 + ks * 64 + ((lane >> 4) * 16)) ^ ((unsigned)(arow & 7) << 4)));
#pragma unroll
      for (int t = 0; t < 8; ++t) {
        const int col = t * 16 + (lane & 15);
        const bf16x8 bv = *(const bf16x8*)(lds + 8192 +
            ((col * 128 + ks * 64 + ((lane >> 4) * 16)) ^ ((unsigned)(col & 7) << 4)));
        acc[t] = __builtin_amdgcn_mfma_f32_16x16x32_bf16(av, bv, acc[t], 0, 0, 0);
      }
    }
  }
  // epilogue: A row-major [r][128] fp32
#pragma unroll
  for (int t = 0; t < 8; ++t) {
    const int col = t * 16 + (lane & 15);
#pragma unroll
    for (int j = 0; j < 4; ++j) {
      const int row = r0 + wave * 16 + (lane >> 4) * 4 + j;
      Aout[row * NM2 + col] = acc[t][j];
    }
  }
}

// ---------------- K2: complex channel mix (fp32 VALU) ----------------
// B[bj,o,k] = sum_i (Ar+iAi)[bj,i,k] * (wr+iwi)[i,o,k];  Bx[r=bj*64+o][k | 64+k] bf16
__global__ __launch_bounds__(256) void k_stage2(const float* __restrict__ A,
                                                const float* __restrict__ wr,
                                                const float* __restrict__ wi,
                                                unsigned short* __restrict__ Bx) {
  __shared__ float sA[4][64][64];   // [bj][i][ 0..31: Ar(k0+c) | 32..63: Ai(k0+c) ]
  const int b = blockIdx.x;
  const int bjc = b >> 2, oh = (b >> 1) & 1, kh = b & 1;
  const int k0 = kh * 32;
  const int tid = threadIdx.x;
#pragma unroll
  for (int p = 0; p < 16; ++p) {
    int fidx = tid + 256 * p;               // float4 index 0..4095
    int row_lin = fidx >> 4, q = fidx & 15;
    int col = (q < 8) ? (k0 + q * 4) : (64 + k0 + (q - 8) * 4);
    f32x4 v = *(const f32x4*)(A + (bjc * 256 + row_lin) * NM2 + col);
    *(f32x4*)(&sA[row_lin >> 6][row_lin & 63][q * 4]) = v;
  }
  __syncthreads();
  const int o_l = tid >> 3, kg = tid & 7;
  const int o = oh * 32 + o_l;
  const int kb = k0 + kg * 4;
  f32x4 accr[4] = {};
  f32x4 acci[4] = {};
  for (int i = 0; i < 64; ++i) {
    f32x4 wrv = *(const f32x4*)(wr + (i * 64 + o) * 64 + kb);
    f32x4 wiv = *(const f32x4*)(wi + (i * 64 + o) * 64 + kb);
#pragma unroll
    for (int bj = 0; bj < 4; ++bj) {
      f32x4 ar = *(const f32x4*)(&sA[bj][i][kg * 4]);
      f32x4 ai = *(const f32x4*)(&sA[bj][i][32 + kg * 4]);
#pragma unroll
      for (int kk = 0; kk < 4; ++kk) {
        accr[bj][kk] += ar[kk] * wrv[kk] - ai[kk] * wiv[kk];
        acci[bj][kk] += ar[kk] * wiv[kk] + ai[kk] * wrv[kk];
      }
    }
  }
#pragma unroll
  for (int bj = 0; bj < 4; ++bj) {
    const int r = (bjc * 4 + bj) * 64 + o;
    uint2 vr; vr.x = pack2(accr[bj][0], accr[bj][1]); vr.y = pack2(accr[bj][2], accr[bj][3]);
    uint2 vi; vi.x = pack2(acci[bj][0], acci[bj][1]); vi.y = pack2(acci[bj][2], acci[bj][3]);
    *(uint2*)(Bx + r * NM2 + kb)      = vr;
    *(uint2*)(Bx + r * NM2 + 64 + kb) = vi;
  }
}

// ---------------- K3: GEMM2  out[16384][2048] = Bx[16384][128] @ T2 ----------------
// BM=128, BN=128, K=128 fully in LDS. 4 waves, wave owns 32 rows x 128 cols.
__global__ __launch_bounds__(256) void k_gemm2(const unsigned short* __restrict__ Bx,
                                               const unsigned short* __restrict__ t2t,
                                               float* __restrict__ out) {
  __shared__ int4 lds4[65536 / 16];
  char* lds = (char*)lds4;
  const int tid = threadIdx.x, wave = tid >> 6, lane = tid & 63;
  const int mb = blockIdx.x >> 4, nb = blockIdx.x & 15;
  const int r0 = mb * 128, n0 = nb * 128;
#pragma unroll
  for (int p = 0; p < 8; ++p) {
    int seg = tid + 256 * p;        // 0..2047
    int row = seg >> 4, part = seg & 15;
    unsigned sw = (unsigned)((row * 256 + part * 16) ^ ((row & 7) << 4));
    int4 va = *(const int4*)(Bx + (r0 + row) * NM2 + part * 8);
    *(int4*)(lds + sw) = va;
    int4 vb = *(const int4*)(t2t + (n0 + row) * NM2 + part * 8);
    *(int4*)(lds + 32768 + sw) = vb;
  }
  __syncthreads();
  f32x4 acc[2][8] = {};
#pragma unroll
  for (int ks = 0; ks < 4; ++ks) {
    const int ar0 = wave * 32 + (lane & 15);
    const int ar1 = ar0 + 16;
    const int koff = ks * 64 + (lane >> 4) * 16;
    bf16x8 a0 = *(const bf16x8*)(lds + ((ar0 * 256 + koff) ^ ((unsigned)(ar0 & 7) << 4)));
    bf16x8 a1 = *(const bf16x8*)(lds + ((ar1 * 256 + koff) ^ ((unsigned)(ar1 & 7) << 4)));
#pragma unroll
    for (int t = 0; t < 8; ++t) {
      const int col = t * 16 + (lane & 15);
      bf16x8 bv = *(const bf16x8*)(lds + 32768 + ((col * 256 + koff) ^ ((unsigned)(col & 7) << 4)));
      acc[0][t] = __builtin_amdgcn_mfma_f32_16x16x32_bf16(a0, bv, acc[0][t], 0, 0, 0);
      acc[1][t] = __builtin_amdgcn_mfma_f32_16x16x32_bf16(a1, bv, acc[1][t], 0, 0, 0);
    }
  }
#pragma unroll
  for (int m = 0; m < 2; ++m) {
#pragma unroll
    for (int t = 0; t < 8; ++t) {
      const int col = n0 + t * 16 + (lane & 15);
#pragma unroll
      for (int j = 0; j < 4; ++j) {
        const int row = r0 + wave * 32 + m * 16 + (lane >> 4) * 4 + j;
        out[row * SEQ + col] = acc[m][t][j];
      }
    }
  }
}

extern "C" void kernel_launch(void* const* d_in, const int* in_sizes, int n_in,
                              void* d_out, int out_size, void* d_ws, size_t ws_size,
                              hipStream_t stream) {
  const float* x  = (const float*)d_in[0];
  const float* wr = (const float*)d_in[1];
  const float* wi = (const float*)d_in[2];
  float* out = (float*)d_out;
  char* ws = (char*)d_ws;
  // ws layout: t1t 512K | t2t 512K | A 8M | Bx 4M  = 13 MB
  unsigned short* t1t = (unsigned short*)(ws);
  unsigned short* t2t = (unsigned short*)(ws + 524288);
  float*          A   = (float*)(ws + 1048576);
  unsigned short* Bx  = (unsigned short*)(ws + 9437184);

  k_tables<<<dim3(1024), dim3(256), 0, stream>>>(t1t, t2t);
  k_gemm1 <<<dim3(256),  dim3(256), 0, stream>>>(x, t1t, A);
  k_stage2<<<dim3(256),  dim3(256), 0, stream>>>(A, wr, wi, Bx);
  k_gemm2 <<<dim3(2048), dim3(256), 0, stream>>>(Bx, t2t, out);
}

// Round 2
// 105.424 us; speedup vs baseline: 1.3180x; 1.3180x over previous
//
#include <hip/hip_runtime.h>
#include <hip/hip_bf16.h>

// SpectralConv1d: out = irfft( pad( einsum('bjix,iox->bjox', rfft(x)[..:64], wr+i*wi) ), n=2048 )
// GEMM1 (DFT, K-split x4, bf16 MFMA) -> stage2 (reduce partials + complex channel mix, fp32)
// -> GEMM2 (inverse DFT, bf16 MFMA).

typedef __bf16 bf16x8 __attribute__((ext_vector_type(8)));
typedef float  f32x4  __attribute__((ext_vector_type(4)));

#define SEQ 2048
#define NM2 128   // 2*MODES (Re | Im planes)
#define KS  4     // K-split factor for GEMM1
#define TWO_PI_OVER_N 3.0679615757712823e-03f

__device__ __forceinline__ unsigned int rnbf(float f) {
  unsigned int u = __builtin_bit_cast(unsigned int, f);
  return (u + 0x7fffu + ((u >> 16) & 1u)) >> 16;  // round-to-nearest-even bf16
}
__device__ __forceinline__ unsigned int pack2(float a, float b) {
  return rnbf(a) | (rnbf(b) << 16);
}

typedef const __attribute__((address_space(1))) unsigned int gu32;
typedef __attribute__((address_space(3))) unsigned int lu32;

// ---------------- K0: trig tables ----------------
// t1sw: 32 tiles of 16 KB; tile kt holds the PRE-SWIZZLED LDS image of
//       T1T[c][kt*64 .. kt*64+63]: byte ((c*128 + part*16) ^ ((c&7)<<4)) + 2*e
//       c<64: cos(2*pi*c*n/N); c>=64: -sin(2*pi*(c-64)*n/N)
// t2t[n][c], c<64: ck*cos; c>=64: -ck*sin  (ck=1/N or 2/N)  [2048][128] bf16 linear
__global__ __launch_bounds__(256) void k_tables(unsigned short* __restrict__ t1sw,
                                                unsigned short* __restrict__ t2t) {
  int idx = blockIdx.x * 256 + threadIdx.x;   // 0..262143
  int c = idx >> 11;                          // 0..127
  int n = idx & 2047;
  int k = c & 63;
  float ph = (float)((k * n) & 2047) * TWO_PI_OVER_N;
  float s, co;
  sincosf(ph, &s, &co);
  float v1 = (c < 64) ? co : -s;
  float ck = (k == 0 ? 1.0f : 2.0f) * (1.0f / 2048.0f);
  float v2 = (c < 64) ? ck * co : -ck * s;
  int kt = n >> 6, part = (n >> 3) & 7, e = n & 7;
  unsigned off = (unsigned)kt * 16384u +
                 (((unsigned)(c * 128 + part * 16)) ^ (((unsigned)c & 7u) << 4)) + 2u * (unsigned)e;
  *(unsigned short*)((char*)t1sw + off) = (unsigned short)rnbf(v1);
  t2t[n * NM2 + c] = (unsigned short)rnbf(v2);
}

// ---------------- K1: GEMM1  P[ks][16384][128] = x[.,Kslice] @ T1[Kslice,.] ----------------
// BM=64, BK=64, N=128 full, K-slice=512 (8 steps). 4 waves, wave owns 16 rows x 128 cols.
__global__ __launch_bounds__(256) void k_gemm1(const float* __restrict__ x,
                                               const unsigned short* __restrict__ t1sw,
                                               float* __restrict__ P) {
  __shared__ int4 lds4[(8192 + 16384) / 16];
  char* lds = (char*)lds4;
  const int tid = threadIdx.x;
  const int wave = tid >> 6, lane = tid & 63;
  const int mtile = blockIdx.x >> 2, ks = blockIdx.x & (KS - 1);
  const int r0 = mtile * 64;
  const int kbase = ks * (SEQ / KS);

  f32x4 acc[8] = {};

  const int row_s = tid >> 2;   // staging: 64 rows, 4 threads/row
  const int q_s = tid & 3;
  const float* xrow = x + (r0 + row_s) * SEQ + kbase + q_s * 16;
  const unsigned xorA = (unsigned)(row_s & 7) << 4;
  const unsigned sA0 = ((unsigned)(row_s * 128 + q_s * 32)) ^ xorA;
  const unsigned sA1 = ((unsigned)(row_s * 128 + q_s * 32 + 16)) ^ xorA;

  const char* t1base = (const char*)t1sw + (size_t)(kbase >> 6) * 16384;

  f32x4 f[4];
#pragma unroll
  for (int m = 0; m < 4; ++m) f[m] = *(const f32x4*)(xrow + m * 4);

  for (int it = 0; it < 8; ++it) {
    __syncthreads();
    // write current x tile (fp32 -> bf16, swizzled)
    unsigned pk[8];
#pragma unroll
    for (int m = 0; m < 4; ++m) {
      pk[2 * m]     = pack2(f[m][0], f[m][1]);
      pk[2 * m + 1] = pack2(f[m][2], f[m][3]);
    }
    uint4 w0; w0.x = pk[0]; w0.y = pk[1]; w0.z = pk[2]; w0.w = pk[3];
    uint4 w1; w1.x = pk[4]; w1.y = pk[5]; w1.z = pk[6]; w1.w = pk[7];
    *(uint4*)(lds + sA0) = w0;
    *(uint4*)(lds + sA1) = w1;
    // T1 tile: pre-swizzled 16 KB image, async DMA to LDS
    const char* tg = t1base + it * 16384;
#pragma unroll
    for (int p = 0; p < 4; ++p) {
      __builtin_amdgcn_global_load_lds((gu32*)(tg + (p * 256 + tid) * 16),
                                       (lu32*)(lds + 8192 + (p * 256 + wave * 64) * 16),
                                       16, 0, 0);
    }
    // prefetch next x tile into regs (flies concurrently with the DMA)
    if (it < 7) {
#pragma unroll
      for (int m = 0; m < 4; ++m) f[m] = *(const f32x4*)(xrow + (it + 1) * 64 + m * 4);
    }
    __syncthreads();
    // compute
#pragma unroll
    for (int kss = 0; kss < 2; ++kss) {
      const int arow = wave * 16 + (lane & 15);
      const bf16x8 av = *(const bf16x8*)(lds +
          ((arow * 128 + kss * 64 + ((lane >> 4) * 16)) ^ ((unsigned)(arow & 7) << 4)));
#pragma unroll
      for (int t = 0; t < 8; ++t) {
        const int col = t * 16 + (lane & 15);
        const bf16x8 bv = *(const bf16x8*)(lds + 8192 +
            ((col * 128 + kss * 64 + ((lane >> 4) * 16)) ^ ((unsigned)(col & 7) << 4)));
        acc[t] = __builtin_amdgcn_mfma_f32_16x16x32_bf16(av, bv, acc[t], 0, 0, 0);
      }
    }
  }
  // epilogue: partial A row-major [r][128] fp32, slice ks
  float* Pout = P + (size_t)ks * (16384 * NM2);
#pragma unroll
  for (int t = 0; t < 8; ++t) {
    const int col = t * 16 + (lane & 15);
#pragma unroll
    for (int j = 0; j < 4; ++j) {
      const int row = r0 + wave * 16 + (lane >> 4) * 4 + j;
      Pout[row * NM2 + col] = acc[t][j];
    }
  }
}

// ---------------- K2: reduce partials + complex channel mix (fp32 VALU) ----------------
// A = sum_ks P[ks]; B[bj,o,k] = sum_i (Ar+iAi)[bj,i,k]*(wr+iwi)[i,o,k]; Bx[r][k|64+k] bf16
__global__ __launch_bounds__(256) void k_stage2(const float* __restrict__ P,
                                                const float* __restrict__ wr,
                                                const float* __restrict__ wi,
                                                unsigned short* __restrict__ Bx) {
  __shared__ float sA[4][64][64];   // [bj][i][ 0..31: Ar(k0+c) | 32..63: Ai(k0+c) ]
  const int b = blockIdx.x;
  const int bjc = b >> 2, oh = (b >> 1) & 1, kh = b & 1;
  const int k0 = kh * 32;
  const int tid = threadIdx.x;
#pragma unroll
  for (int p = 0; p < 16; ++p) {
    int fidx = tid + 256 * p;               // float4 index 0..4095
    int row_lin = fidx >> 4, q = fidx & 15;
    int col = (q < 8) ? (k0 + q * 4) : (64 + k0 + (q - 8) * 4);
    const float* base = P + (size_t)(bjc * 256 + row_lin) * NM2 + col;
    f32x4 v0 = *(const f32x4*)(base);
    f32x4 v1 = *(const f32x4*)(base + 1 * 16384 * NM2);
    f32x4 v2 = *(const f32x4*)(base + 2 * 16384 * NM2);
    f32x4 v3 = *(const f32x4*)(base + 3 * 16384 * NM2);
    f32x4 v = (v0 + v1) + (v2 + v3);
    *(f32x4*)(&sA[row_lin >> 6][row_lin & 63][q * 4]) = v;
  }
  __syncthreads();
  const int o_l = tid >> 3, kg = tid & 7;
  const int o = oh * 32 + o_l;
  const int kb = k0 + kg * 4;
  f32x4 accr[4] = {};
  f32x4 acci[4] = {};
  for (int i = 0; i < 64; ++i) {
    f32x4 wrv = *(const f32x4*)(wr + (i * 64 + o) * 64 + kb);
    f32x4 wiv = *(const f32x4*)(wi + (i * 64 + o) * 64 + kb);
#pragma unroll
    for (int bj = 0; bj < 4; ++bj) {
      f32x4 ar = *(const f32x4*)(&sA[bj][i][kg * 4]);
      f32x4 ai = *(const f32x4*)(&sA[bj][i][32 + kg * 4]);
#pragma unroll
      for (int kk = 0; kk < 4; ++kk) {
        accr[bj][kk] += ar[kk] * wrv[kk] - ai[kk] * wiv[kk];
        acci[bj][kk] += ar[kk] * wiv[kk] + ai[kk] * wrv[kk];
      }
    }
  }
#pragma unroll
  for (int bj = 0; bj < 4; ++bj) {
    const int r = (bjc * 4 + bj) * 64 + o;
    uint2 vr; vr.x = pack2(accr[bj][0], accr[bj][1]); vr.y = pack2(accr[bj][2], accr[bj][3]);
    uint2 vi; vi.x = pack2(acci[bj][0], acci[bj][1]); vi.y = pack2(acci[bj][2], acci[bj][3]);
    *(uint2*)(Bx + r * NM2 + kb)      = vr;
    *(uint2*)(Bx + r * NM2 + 64 + kb) = vi;
  }
}

// ---------------- K3: GEMM2  out[16384][2048] = Bx[16384][128] @ T2 ----------------
// BM=128, BN=128, K=128 fully in LDS. 4 waves, wave owns 32 rows x 128 cols.
__global__ __launch_bounds__(256) void k_gemm2(const unsigned short* __restrict__ Bx,
                                               const unsigned short* __restrict__ t2t,
                                               float* __restrict__ out) {
  __shared__ int4 lds4[65536 / 16];
  char* lds = (char*)lds4;
  const int tid = threadIdx.x, wave = tid >> 6, lane = tid & 63;
  const int mb = blockIdx.x >> 4, nb = blockIdx.x & 15;
  const int r0 = mb * 128, n0 = nb * 128;
#pragma unroll
  for (int p = 0; p < 8; ++p) {
    int seg = tid + 256 * p;        // 0..2047
    int row = seg >> 4, part = seg & 15;
    unsigned sw = (unsigned)((row * 256 + part * 16) ^ ((row & 7) << 4));
    int4 va = *(const int4*)(Bx + (r0 + row) * NM2 + part * 8);
    *(int4*)(lds + sw) = va;
    int4 vb = *(const int4*)(t2t + (n0 + row) * NM2 + part * 8);
    *(int4*)(lds + 32768 + sw) = vb;
  }
  __syncthreads();
  f32x4 acc[2][8] = {};
#pragma unroll
  for (int ks = 0; ks < 4; ++ks) {
    const int ar0 = wave * 32 + (lane & 15);
    const int ar1 = ar0 + 16;
    const int koff = ks * 64 + (lane >> 4) * 16;
    bf16x8 a0 = *(const bf16x8*)(lds + ((ar0 * 256 + koff) ^ ((unsigned)(ar0 & 7) << 4)));
    bf16x8 a1 = *(const bf16x8*)(lds + ((ar1 * 256 + koff) ^ ((unsigned)(ar1 & 7) << 4)));
#pragma unroll
    for (int t = 0; t < 8; ++t) {
      const int col = t * 16 + (lane & 15);
      bf16x8 bv = *(const bf16x8*)(lds + 32768 + ((col * 256 + koff) ^ ((unsigned)(col & 7) << 4)));
      acc[0][t] = __builtin_amdgcn_mfma_f32_16x16x32_bf16(a0, bv, acc[0][t], 0, 0, 0);
      acc[1][t] = __builtin_amdgcn_mfma_f32_16x16x32_bf16(a1, bv, acc[1][t], 0, 0, 0);
    }
  }
#pragma unroll
  for (int m = 0; m < 2; ++m) {
#pragma unroll
    for (int t = 0; t < 8; ++t) {
      const int col = n0 + t * 16 + (lane & 15);
#pragma unroll
      for (int j = 0; j < 4; ++j) {
        const int row = r0 + wave * 32 + m * 16 + (lane >> 4) * 4 + j;
        out[row * SEQ + col] = acc[m][t][j];
      }
    }
  }
}

extern "C" void kernel_launch(void* const* d_in, const int* in_sizes, int n_in,
                              void* d_out, int out_size, void* d_ws, size_t ws_size,
                              hipStream_t stream) {
  const float* x  = (const float*)d_in[0];
  const float* wr = (const float*)d_in[1];
  const float* wi = (const float*)d_in[2];
  float* out = (float*)d_out;
  char* ws = (char*)d_ws;
  // ws layout: t1sw 512K | t2t 512K | P 4x8M = 32M | Bx 4M   (total 37 MB)
  unsigned short* t1sw = (unsigned short*)(ws);
  unsigned short* t2t  = (unsigned short*)(ws + 524288);
  float*          P    = (float*)(ws + 1048576);
  unsigned short* Bx   = (unsigned short*)(ws + 1048576 + (size_t)KS * 16384 * NM2 * 4);

  k_tables<<<dim3(1024), dim3(256), 0, stream>>>(t1sw, t2t);
  k_gemm1 <<<dim3(256 * KS), dim3(256), 0, stream>>>(x, t1sw, P);
  k_stage2<<<dim3(256),  dim3(256), 0, stream>>>(P, wr, wi, Bx);
  k_gemm2 <<<dim3(2048), dim3(256), 0, stream>>>(Bx, t2t, out);
}

// Round 3
// 103.825 us; speedup vs baseline: 1.3383x; 1.0154x over previous
//
#include <hip/hip_runtime.h>
#include <hip/hip_bf16.h>

// SpectralConv1d: out = irfft( pad( einsum('bjix,iox->bjox', rfft(x)[..:64], wr+i*wi) ), n=2048 )
// GEMM1 (DFT, K-split x4, bf16 MFMA, 2-phase pipelined) -> stage2 (reduce bf16 partials +
// complex channel mix, fp32) -> GEMM2 (inverse DFT, bf16 MFMA).

typedef __bf16 bf16x8 __attribute__((ext_vector_type(8)));
typedef float  f32x4  __attribute__((ext_vector_type(4)));

#define SEQ 2048
#define NM2 128   // 2*MODES (Re | Im planes)
#define KS  4     // K-split factor for GEMM1
#define TWO_PI_OVER_N 3.0679615757712823e-03f

__device__ __forceinline__ unsigned int rnbf(float f) {
  unsigned int u = __builtin_bit_cast(unsigned int, f);
  return (u + 0x7fffu + ((u >> 16) & 1u)) >> 16;  // round-to-nearest-even bf16
}
__device__ __forceinline__ unsigned int pack2(float a, float b) {
  return rnbf(a) | (rnbf(b) << 16);
}
__device__ __forceinline__ float frombf(unsigned int lo16_in_place) {
  return __builtin_bit_cast(float, lo16_in_place);
}

typedef const __attribute__((address_space(1))) unsigned int gu32;
typedef __attribute__((address_space(3))) unsigned int lu32;

// ---------------- K0: trig tables ----------------
// t1sw: 32 tiles of 16 KB; tile kt holds the PRE-SWIZZLED LDS image of
//       T1T[c][kt*64 .. kt*64+63]: byte ((c*128 + part*16) ^ ((c&7)<<4)) + 2*e
//       c<64: cos(2*pi*c*n/N); c>=64: -sin(2*pi*(c-64)*n/N)
// t2t[n][c], c<64: ck*cos; c>=64: -ck*sin  (ck=1/N or 2/N)  [2048][128] bf16 linear
__global__ __launch_bounds__(256) void k_tables(unsigned short* __restrict__ t1sw,
                                                unsigned short* __restrict__ t2t) {
  int idx = blockIdx.x * 256 + threadIdx.x;   // 0..262143
  int c = idx >> 11;                          // 0..127
  int n = idx & 2047;
  int k = c & 63;
  float ph = (float)((k * n) & 2047) * TWO_PI_OVER_N;
  float s, co;
  sincosf(ph, &s, &co);
  float v1 = (c < 64) ? co : -s;
  float ck = (k == 0 ? 1.0f : 2.0f) * (1.0f / 2048.0f);
  float v2 = (c < 64) ? ck * co : -ck * s;
  int kt = n >> 6, part = (n >> 3) & 7, e = n & 7;
  unsigned off = (unsigned)kt * 16384u +
                 (((unsigned)(c * 128 + part * 16)) ^ (((unsigned)c & 7u) << 4)) + 2u * (unsigned)e;
  *(unsigned short*)((char*)t1sw + off) = (unsigned short)rnbf(v1);
  t2t[n * NM2 + c] = (unsigned short)rnbf(v2);
}

// ---------------- K1: GEMM1  P[ks][16384][128] = x[.,Kslice] @ T1[Kslice,.]  (bf16 out) ----
// BM=64, BK=64, N=128 full, K-slice=512 (8 steps). 4 waves, wave owns 16 rows x 128 cols.
// 2-phase pipeline: double-buffered LDS (x: 2x8KB, t1: 2x16KB = 48 KB), STAGE(t+1) issued
// before compute(t), ds_write of x after compute, ONE barrier per iteration.
__global__ __launch_bounds__(256) void k_gemm1(const float* __restrict__ x,
                                               const unsigned short* __restrict__ t1sw,
                                               unsigned short* __restrict__ P) {
  __shared__ int4 lds4[49152 / 16];   // [0,16K): xbuf0/1 ; [16K,48K): t1buf0/1
  char* lds = (char*)lds4;
  const int tid = threadIdx.x;
  const int wave = tid >> 6, lane = tid & 63;
  const int mtile = blockIdx.x >> 2, ks = blockIdx.x & (KS - 1);
  const int r0 = mtile * 64;
  const int kbase = ks * (SEQ / KS);

  f32x4 acc[8] = {};

  const int row_s = tid >> 2;   // staging: 64 rows, 4 threads/row
  const int q_s = tid & 3;
  const float* xrow = x + (size_t)(r0 + row_s) * SEQ + kbase + q_s * 16;
  const unsigned xorA = (unsigned)(row_s & 7) << 4;
  const unsigned sA0 = ((unsigned)(row_s * 128 + q_s * 32)) ^ xorA;
  const unsigned sA1 = ((unsigned)(row_s * 128 + q_s * 32 + 16)) ^ xorA;

  const char* t1base = (const char*)t1sw + (size_t)(kbase >> 6) * 16384;

  // ---- prologue: stage tile 0 into buffer 0 ----
  f32x4 f[4];
#pragma unroll
  for (int m = 0; m < 4; ++m) f[m] = *(const f32x4*)(xrow + m * 4);
#pragma unroll
  for (int p = 0; p < 4; ++p) {
    __builtin_amdgcn_global_load_lds((gu32*)(t1base + (p * 256 + tid) * 16),
                                     (lu32*)(lds + 16384 + (p * 256 + wave * 64) * 16),
                                     16, 0, 0);
  }
  {
    unsigned pk[8];
#pragma unroll
    for (int m = 0; m < 4; ++m) {
      pk[2 * m]     = pack2(f[m][0], f[m][1]);
      pk[2 * m + 1] = pack2(f[m][2], f[m][3]);
    }
    uint4 w0; w0.x = pk[0]; w0.y = pk[1]; w0.z = pk[2]; w0.w = pk[3];
    uint4 w1; w1.x = pk[4]; w1.y = pk[5]; w1.z = pk[6]; w1.w = pk[7];
    *(uint4*)(lds + sA0) = w0;
    *(uint4*)(lds + sA1) = w1;
  }
  __syncthreads();

  for (int it = 0; it < 8; ++it) {
    const int cur = it & 1, nxt = cur ^ 1;
    const int xoff = cur * 8192;
    const int toff = 16384 + cur * 16384;
    // ---- issue STAGE(it+1) before compute(it) ----
    if (it < 7) {
      const char* tg = t1base + (it + 1) * 16384;
#pragma unroll
      for (int p = 0; p < 4; ++p) {
        __builtin_amdgcn_global_load_lds((gu32*)(tg + (p * 256 + tid) * 16),
                                         (lu32*)(lds + 16384 + nxt * 16384 + (p * 256 + wave * 64) * 16),
                                         16, 0, 0);
      }
#pragma unroll
      for (int m = 0; m < 4; ++m) f[m] = *(const f32x4*)(xrow + (it + 1) * 64 + m * 4);
    }
    // ---- compute tile it ----
#pragma unroll
    for (int kss = 0; kss < 2; ++kss) {
      const int arow = wave * 16 + (lane & 15);
      const bf16x8 av = *(const bf16x8*)(lds + xoff +
          ((arow * 128 + kss * 64 + ((lane >> 4) * 16)) ^ ((unsigned)(arow & 7) << 4)));
#pragma unroll
      for (int t = 0; t < 8; ++t) {
        const int col = t * 16 + (lane & 15);
        const bf16x8 bv = *(const bf16x8*)(lds + toff +
            ((col * 128 + kss * 64 + ((lane >> 4) * 16)) ^ ((unsigned)(col & 7) << 4)));
        acc[t] = __builtin_amdgcn_mfma_f32_16x16x32_bf16(av, bv, acc[t], 0, 0, 0);
      }
    }
    // ---- write-late: x(it+1) into nxt buffer, then the single barrier ----
    if (it < 7) {
      unsigned pk[8];
#pragma unroll
      for (int m = 0; m < 4; ++m) {
        pk[2 * m]     = pack2(f[m][0], f[m][1]);
        pk[2 * m + 1] = pack2(f[m][2], f[m][3]);
      }
      uint4 w0; w0.x = pk[0]; w0.y = pk[1]; w0.z = pk[2]; w0.w = pk[3];
      uint4 w1; w1.x = pk[4]; w1.y = pk[5]; w1.z = pk[6]; w1.w = pk[7];
      *(uint4*)(lds + nxt * 8192 + sA0) = w0;
      *(uint4*)(lds + nxt * 8192 + sA1) = w1;
    }
    __syncthreads();
  }
  // epilogue: partial A row-major [r][128] bf16, slice ks
  unsigned short* Pout = P + (size_t)ks * (16384 * NM2);
#pragma unroll
  for (int t = 0; t < 8; ++t) {
    const int col = t * 16 + (lane & 15);
#pragma unroll
    for (int j = 0; j < 4; ++j) {
      const int row = r0 + wave * 16 + (lane >> 4) * 4 + j;
      Pout[row * NM2 + col] = (unsigned short)rnbf(acc[t][j]);
    }
  }
}

// ---------------- K2: reduce bf16 partials + complex channel mix (fp32 VALU) ----------------
// A = sum_ks P[ks]; B[bj,o,k] = sum_i (Ar+iAi)[bj,i,k]*(wr+iwi)[i,o,k]; Bx[r][k|64+k] bf16
__global__ __launch_bounds__(256) void k_stage2(const unsigned short* __restrict__ P,
                                                const float* __restrict__ wr,
                                                const float* __restrict__ wi,
                                                unsigned short* __restrict__ Bx) {
  __shared__ float sA[4][64][64];   // [bj][i][ 0..31: Ar(k0+c) | 32..63: Ai(k0+c) ]
  const int b = blockIdx.x;
  const int bjc = b >> 2, oh = (b >> 1) & 1, kh = b & 1;
  const int k0 = kh * 32;
  const int tid = threadIdx.x;
#pragma unroll
  for (int p = 0; p < 16; ++p) {
    int fidx = tid + 256 * p;               // quad index 0..4095
    int row_lin = fidx >> 4, q = fidx & 15;
    int col = (q < 8) ? (k0 + q * 4) : (64 + k0 + (q - 8) * 4);
    const unsigned short* base = P + (size_t)(bjc * 256 + row_lin) * NM2 + col;
    f32x4 v = {};
#pragma unroll
    for (int s = 0; s < KS; ++s) {
      uint2 u = *(const uint2*)(base + (size_t)s * (16384 * NM2));
      v[0] += frombf(u.x << 16);
      v[1] += frombf(u.x & 0xffff0000u);
      v[2] += frombf(u.y << 16);
      v[3] += frombf(u.y & 0xffff0000u);
    }
    *(f32x4*)(&sA[row_lin >> 6][row_lin & 63][q * 4]) = v;
  }
  __syncthreads();
  const int o_l = tid >> 3, kg = tid & 7;
  const int o = oh * 32 + o_l;
  const int kb = k0 + kg * 4;
  f32x4 accr[4] = {};
  f32x4 acci[4] = {};
  for (int i = 0; i < 64; ++i) {
    f32x4 wrv = *(const f32x4*)(wr + (i * 64 + o) * 64 + kb);
    f32x4 wiv = *(const f32x4*)(wi + (i * 64 + o) * 64 + kb);
#pragma unroll
    for (int bj = 0; bj < 4; ++bj) {
      f32x4 ar = *(const f32x4*)(&sA[bj][i][kg * 4]);
      f32x4 ai = *(const f32x4*)(&sA[bj][i][32 + kg * 4]);
#pragma unroll
      for (int kk = 0; kk < 4; ++kk) {
        accr[bj][kk] += ar[kk] * wrv[kk] - ai[kk] * wiv[kk];
        acci[bj][kk] += ar[kk] * wiv[kk] + ai[kk] * wrv[kk];
      }
    }
  }
#pragma unroll
  for (int bj = 0; bj < 4; ++bj) {
    const int r = (bjc * 4 + bj) * 64 + o;
    uint2 vr; vr.x = pack2(accr[bj][0], accr[bj][1]); vr.y = pack2(accr[bj][2], accr[bj][3]);
    uint2 vi; vi.x = pack2(acci[bj][0], acci[bj][1]); vi.y = pack2(acci[bj][2], acci[bj][3]);
    *(uint2*)(Bx + r * NM2 + kb)      = vr;
    *(uint2*)(Bx + r * NM2 + 64 + kb) = vi;
  }
}

// ---------------- K3: GEMM2  out[16384][2048] = Bx[16384][128] @ T2 ----------------
// BM=128, BN=128, K=128 fully in LDS. 4 waves, wave owns 32 rows x 128 cols.
__global__ __launch_bounds__(256) void k_gemm2(const unsigned short* __restrict__ Bx,
                                               const unsigned short* __restrict__ t2t,
                                               float* __restrict__ out) {
  __shared__ int4 lds4[65536 / 16];
  char* lds = (char*)lds4;
  const int tid = threadIdx.x, wave = tid >> 6, lane = tid & 63;
  const int mb = blockIdx.x >> 4, nb = blockIdx.x & 15;
  const int r0 = mb * 128, n0 = nb * 128;
#pragma unroll
  for (int p = 0; p < 8; ++p) {
    int seg = tid + 256 * p;        // 0..2047
    int row = seg >> 4, part = seg & 15;
    unsigned sw = (unsigned)((row * 256 + part * 16) ^ ((row & 7) << 4));
    int4 va = *(const int4*)(Bx + (r0 + row) * NM2 + part * 8);
    *(int4*)(lds + sw) = va;
    int4 vb = *(const int4*)(t2t + (n0 + row) * NM2 + part * 8);
    *(int4*)(lds + 32768 + sw) = vb;
  }
  __syncthreads();
  f32x4 acc[2][8] = {};
#pragma unroll
  for (int ks = 0; ks < 4; ++ks) {
    const int ar0 = wave * 32 + (lane & 15);
    const int ar1 = ar0 + 16;
    const int koff = ks * 64 + (lane >> 4) * 16;
    bf16x8 a0 = *(const bf16x8*)(lds + ((ar0 * 256 + koff) ^ ((unsigned)(ar0 & 7) << 4)));
    bf16x8 a1 = *(const bf16x8*)(lds + ((ar1 * 256 + koff) ^ ((unsigned)(ar1 & 7) << 4)));
#pragma unroll
    for (int t = 0; t < 8; ++t) {
      const int col = t * 16 + (lane & 15);
      bf16x8 bv = *(const bf16x8*)(lds + 32768 + ((col * 256 + koff) ^ ((unsigned)(col & 7) << 4)));
      acc[0][t] = __builtin_amdgcn_mfma_f32_16x16x32_bf16(a0, bv, acc[0][t], 0, 0, 0);
      acc[1][t] = __builtin_amdgcn_mfma_f32_16x16x32_bf16(a1, bv, acc[1][t], 0, 0, 0);
    }
  }
#pragma unroll
  for (int m = 0; m < 2; ++m) {
#pragma unroll
    for (int t = 0; t < 8; ++t) {
      const int col = n0 + t * 16 + (lane & 15);
#pragma unroll
      for (int j = 0; j < 4; ++j) {
        const int row = r0 + wave * 32 + m * 16 + (lane >> 4) * 4 + j;
        out[row * SEQ + col] = acc[m][t][j];
      }
    }
  }
}

extern "C" void kernel_launch(void* const* d_in, const int* in_sizes, int n_in,
                              void* d_out, int out_size, void* d_ws, size_t ws_size,
                              hipStream_t stream) {
  const float* x  = (const float*)d_in[0];
  const float* wr = (const float*)d_in[1];
  const float* wi = (const float*)d_in[2];
  float* out = (float*)d_out;
  char* ws = (char*)d_ws;
  // ws layout: t1sw 512K | t2t 512K | P (bf16) 4x4M = 16M | Bx 4M   (total 21 MB)
  unsigned short* t1sw = (unsigned short*)(ws);
  unsigned short* t2t  = (unsigned short*)(ws + 524288);
  unsigned short* P    = (unsigned short*)(ws + 1048576);
  unsigned short* Bx   = (unsigned short*)(ws + 1048576 + (size_t)KS * 16384 * NM2 * 2);

  k_tables<<<dim3(1024), dim3(256), 0, stream>>>(t1sw, t2t);
  k_gemm1 <<<dim3(256 * KS), dim3(256), 0, stream>>>(x, t1sw, P);
  k_stage2<<<dim3(256),  dim3(256), 0, stream>>>(P, wr, wi, Bx);
  k_gemm2 <<<dim3(2048), dim3(256), 0, stream>>>(Bx, t2t, out);
}

// Round 4
// 89.931 us; speedup vs baseline: 1.5451x; 1.1545x over previous
//
#include <hip/hip_runtime.h>
#include <hip/hip_bf16.h>

// SpectralConv1d: out = irfft( pad( einsum('bjix,iox->bjox', rfft(x)[..:64], wr+i*wi) ), n=2048 )
// GEMM1 (DFT, K-split x2, pure-DMA staging: fp32 x + pre-swizzled bf16 T1, cvt at read)
// -> stage2 (reduce bf16 partials + complex channel mix, fp32) -> GEMM2 (inverse DFT).

typedef __bf16 bf16x8 __attribute__((ext_vector_type(8)));
typedef float  f32x4  __attribute__((ext_vector_type(4)));

#define SEQ 2048
#define NM2 128   // 2*MODES (Re | Im planes)
#define KS  2     // K-split factor for GEMM1
#define TWO_PI_OVER_N 3.0679615757712823e-03f

__device__ __forceinline__ unsigned int rnbf(float f) {
  unsigned int u = __builtin_bit_cast(unsigned int, f);
  return (u + 0x7fffu + ((u >> 16) & 1u)) >> 16;  // round-to-nearest-even bf16
}
__device__ __forceinline__ unsigned int pack2(float a, float b) {
  return rnbf(a) | (rnbf(b) << 16);
}
__device__ __forceinline__ float frombf(unsigned int lo16_in_place) {
  return __builtin_bit_cast(float, lo16_in_place);
}

typedef const __attribute__((address_space(1))) unsigned int gu32;
typedef __attribute__((address_space(3))) unsigned int lu32;

// ---------------- K0: trig tables ----------------
// t1sw: 32 tiles of 16 KB; tile kt = PRE-SWIZZLED LDS image of T1T[c][kt*64..+63]:
//       byte ((c*128 + part*16) ^ ((c&7)<<4)) + 2*e ; c<64: cos ; c>=64: -sin
// t2t[n][c], c<64: ck*cos; c>=64: -ck*sin  (ck=1/N or 2/N)  [2048][128] bf16 linear
__global__ __launch_bounds__(256) void k_tables(unsigned short* __restrict__ t1sw,
                                                unsigned short* __restrict__ t2t) {
  int idx = blockIdx.x * 256 + threadIdx.x;   // 0..262143
  int c = idx >> 11;                          // 0..127
  int n = idx & 2047;
  int k = c & 63;
  float ph = (float)((k * n) & 2047) * TWO_PI_OVER_N;
  float s, co;
  sincosf(ph, &s, &co);
  float v1 = (c < 64) ? co : -s;
  float ck = (k == 0 ? 1.0f : 2.0f) * (1.0f / 2048.0f);
  float v2 = (c < 64) ? ck * co : -ck * s;
  int kt = n >> 6, part = (n >> 3) & 7, e = n & 7;
  unsigned off = (unsigned)kt * 16384u +
                 (((unsigned)(c * 128 + part * 16)) ^ (((unsigned)c & 7u) << 4)) + 2u * (unsigned)e;
  *(unsigned short*)((char*)t1sw + off) = (unsigned short)rnbf(v1);
  t2t[n * NM2 + c] = (unsigned short)rnbf(v2);
}

// ---------------- K1: GEMM1  P[ks][16384][128] = x[.,Kslice] @ T1[Kslice,.]  (bf16 out) ----
// BM=64, BK=64, K-slice=1024 (16 iters). 4 waves; wave owns 16 rows x 128 cols.
// ALL staging via global_load_lds (single vmcnt domain): x fp32 tile [64][64] (16KB,
// source pre-swizzled per-lane so LDS image carries the XOR swizzle), T1 bf16 tile (16KB,
// pre-swizzled global image). Double-buffered: 64 KB LDS, 2 blocks/CU, grid = 512 exact.
// fp32->bf16 conversion happens at A-fragment read: 4x ds_read_b128 + 8x v_cvt_pk_bf16_f32.
__global__ __launch_bounds__(256) void k_gemm1(const float* __restrict__ x,
                                               const unsigned short* __restrict__ t1sw,
                                               unsigned short* __restrict__ P) {
  __shared__ int4 lds4[65536 / 16];  // [0,32K): xbuf0/1 fp32 ; [32K,64K): t1buf0/1 bf16
  char* lds = (char*)lds4;
  const int tid = threadIdx.x, wave = tid >> 6, lane = tid & 63;
  const int mtile = blockIdx.x >> 1, ks = blockIdx.x & (KS - 1);
  const int r0 = mtile * 64;
  const int kbase = ks * (SEQ / KS);
  const char* t1base = (const char*)t1sw + (size_t)(kbase >> 6) * 16384;

  // per-lane x source pointers: DMA p stages rows p*16+wave*4+(lane>>4); the 16B unit
  // within the row is (lane&15)^(row&7)  -> LDS linear dest == swizzled image.
  const float* xsrc[4];
#pragma unroll
  for (int p = 0; p < 4; ++p) {
    const int row = p * 16 + wave * 4 + (lane >> 4);
    const int u = (lane & 15) ^ (row & 7);
    xsrc[p] = x + (size_t)(r0 + row) * SEQ + kbase + u * 4;
  }

  f32x4 acc[8] = {};

  // ---- prologue: stage tile 0 ----
#pragma unroll
  for (int p = 0; p < 4; ++p)
    __builtin_amdgcn_global_load_lds((gu32*)(xsrc[p]),
                                     (lu32*)(lds + p * 4096 + wave * 1024), 16, 0, 0);
#pragma unroll
  for (int p = 0; p < 4; ++p)
    __builtin_amdgcn_global_load_lds((gu32*)(t1base + (p * 256 + tid) * 16),
                                     (lu32*)(lds + 32768 + (p * 256 + wave * 64) * 16), 16, 0, 0);
  asm volatile("s_waitcnt vmcnt(0)" ::: "memory");
  __builtin_amdgcn_s_barrier();

  const int a = wave * 16 + (lane & 15);
  const unsigned xra = (unsigned)(a & 7) << 4;
  const int kg = lane >> 4;

  for (int it = 0; it < 16; ++it) {
    const int cur = it & 1, nxt = cur ^ 1;
    const int xoff = cur * 16384;
    const int toff = 32768 + cur * 16384;
    // ---- issue STAGE(it+1) (8 DMA ops, they fly across the whole compute phase) ----
    if (it < 15) {
      const char* tg = t1base + (it + 1) * 16384;
#pragma unroll
      for (int p = 0; p < 4; ++p)
        __builtin_amdgcn_global_load_lds((gu32*)(xsrc[p] + (it + 1) * 64),
                                         (lu32*)(lds + nxt * 16384 + p * 4096 + wave * 1024),
                                         16, 0, 0);
#pragma unroll
      for (int p = 0; p < 4; ++p)
        __builtin_amdgcn_global_load_lds((gu32*)(tg + (p * 256 + tid) * 16),
                                         (lu32*)(lds + 32768 + nxt * 16384 + (p * 256 + wave * 64) * 16),
                                         16, 0, 0);
    }
    // ---- compute tile it ----
#pragma unroll
    for (int kss = 0; kss < 2; ++kss) {
      const unsigned byte0 = (unsigned)(a * 256 + kss * 128 + kg * 32);
      const f32x4 lo = *(const f32x4*)(lds + xoff + (byte0 ^ xra));
      const f32x4 hi = *(const f32x4*)(lds + xoff + ((byte0 + 16) ^ xra));
      unsigned c0, c1, c2, c3;
      asm("v_cvt_pk_bf16_f32 %0, %1, %2" : "=v"(c0) : "v"(lo[0]), "v"(lo[1]));
      asm("v_cvt_pk_bf16_f32 %0, %1, %2" : "=v"(c1) : "v"(lo[2]), "v"(lo[3]));
      asm("v_cvt_pk_bf16_f32 %0, %1, %2" : "=v"(c2) : "v"(hi[0]), "v"(hi[1]));
      asm("v_cvt_pk_bf16_f32 %0, %1, %2" : "=v"(c3) : "v"(hi[2]), "v"(hi[3]));
      uint4 pk; pk.x = c0; pk.y = c1; pk.z = c2; pk.w = c3;
      const bf16x8 av = __builtin_bit_cast(bf16x8, pk);
#pragma unroll
      for (int t = 0; t < 8; ++t) {
        const int col = t * 16 + (lane & 15);
        const bf16x8 bv = *(const bf16x8*)(lds + toff +
            ((col * 128 + kss * 64 + kg * 16) ^ ((unsigned)(col & 7) << 4)));
        acc[t] = __builtin_amdgcn_mfma_f32_16x16x32_bf16(av, bv, acc[t], 0, 0, 0);
      }
    }
    // ---- single barrier per iter; DMA(it+1) had the whole compute phase to land ----
    asm volatile("s_waitcnt vmcnt(0)" ::: "memory");
    __builtin_amdgcn_s_barrier();
  }
  // epilogue: partial A row-major [r][128] bf16, slice ks
  unsigned short* Pout = P + (size_t)ks * (16384 * NM2);
#pragma unroll
  for (int t = 0; t < 8; ++t) {
    const int col = t * 16 + (lane & 15);
#pragma unroll
    for (int j = 0; j < 4; ++j) {
      const int row = r0 + wave * 16 + (lane >> 4) * 4 + j;
      Pout[row * NM2 + col] = (unsigned short)rnbf(acc[t][j]);
    }
  }
}

// ---------------- K2: reduce bf16 partials + complex channel mix (fp32 VALU) ----------------
// A = sum_ks P[ks]; B[bj,o,k] = sum_i (Ar+iAi)[bj,i,k]*(wr+iwi)[i,o,k]; Bx[r][k|64+k] bf16
__global__ __launch_bounds__(256) void k_stage2(const unsigned short* __restrict__ P,
                                                const float* __restrict__ wr,
                                                const float* __restrict__ wi,
                                                unsigned short* __restrict__ Bx) {
  __shared__ float sA[4][64][64];   // [bj][i][ 0..31: Ar(k0+c) | 32..63: Ai(k0+c) ]
  const int b = blockIdx.x;
  const int bjc = b >> 2, oh = (b >> 1) & 1, kh = b & 1;
  const int k0 = kh * 32;
  const int tid = threadIdx.x;
#pragma unroll
  for (int p = 0; p < 16; ++p) {
    int fidx = tid + 256 * p;               // quad index 0..4095
    int row_lin = fidx >> 4, q = fidx & 15;
    int col = (q < 8) ? (k0 + q * 4) : (64 + k0 + (q - 8) * 4);
    const unsigned short* base = P + (size_t)(bjc * 256 + row_lin) * NM2 + col;
    f32x4 v = {};
#pragma unroll
    for (int s = 0; s < KS; ++s) {
      uint2 u = *(const uint2*)(base + (size_t)s * (16384 * NM2));
      v[0] += frombf(u.x << 16);
      v[1] += frombf(u.x & 0xffff0000u);
      v[2] += frombf(u.y << 16);
      v[3] += frombf(u.y & 0xffff0000u);
    }
    *(f32x4*)(&sA[row_lin >> 6][row_lin & 63][q * 4]) = v;
  }
  __syncthreads();
  const int o_l = tid >> 3, kg = tid & 7;
  const int o = oh * 32 + o_l;
  const int kb = k0 + kg * 4;
  f32x4 accr[4] = {};
  f32x4 acci[4] = {};
  for (int i = 0; i < 64; ++i) {
    f32x4 wrv = *(const f32x4*)(wr + (i * 64 + o) * 64 + kb);
    f32x4 wiv = *(const f32x4*)(wi + (i * 64 + o) * 64 + kb);
#pragma unroll
    for (int bj = 0; bj < 4; ++bj) {
      f32x4 ar = *(const f32x4*)(&sA[bj][i][kg * 4]);
      f32x4 ai = *(const f32x4*)(&sA[bj][i][32 + kg * 4]);
#pragma unroll
      for (int kk = 0; kk < 4; ++kk) {
        accr[bj][kk] += ar[kk] * wrv[kk] - ai[kk] * wiv[kk];
        acci[bj][kk] += ar[kk] * wiv[kk] + ai[kk] * wrv[kk];
      }
    }
  }
#pragma unroll
  for (int bj = 0; bj < 4; ++bj) {
    const int r = (bjc * 4 + bj) * 64 + o;
    uint2 vr; vr.x = pack2(accr[bj][0], accr[bj][1]); vr.y = pack2(accr[bj][2], accr[bj][3]);
    uint2 vi; vi.x = pack2(acci[bj][0], acci[bj][1]); vi.y = pack2(acci[bj][2], acci[bj][3]);
    *(uint2*)(Bx + r * NM2 + kb)      = vr;
    *(uint2*)(Bx + r * NM2 + 64 + kb) = vi;
  }
}

// ---------------- K3: GEMM2  out[16384][2048] = Bx[16384][128] @ T2 ----------------
// BM=128, BN=128, K=128 fully in LDS. 4 waves; wave owns 32 rows x 128 cols.
// XCD-aware block swizzle (2048 % 8 == 0 -> simple bijective form).
__global__ __launch_bounds__(256) void k_gemm2(const unsigned short* __restrict__ Bx,
                                               const unsigned short* __restrict__ t2t,
                                               float* __restrict__ out) {
  __shared__ int4 lds4[65536 / 16];
  char* lds = (char*)lds4;
  const int tid = threadIdx.x, wave = tid >> 6, lane = tid & 63;
  const int swz = (blockIdx.x & 7) * 256 + (blockIdx.x >> 3);   // XCD-contiguous
  const int mb = swz >> 4, nb = swz & 15;
  const int r0 = mb * 128, n0 = nb * 128;
#pragma unroll
  for (int p = 0; p < 8; ++p) {
    int seg = tid + 256 * p;        // 0..2047
    int row = seg >> 4, part = seg & 15;
    unsigned sw = (unsigned)((row * 256 + part * 16) ^ ((row & 7) << 4));
    int4 va = *(const int4*)(Bx + (r0 + row) * NM2 + part * 8);
    *(int4*)(lds + sw) = va;
    int4 vb = *(const int4*)(t2t + (n0 + row) * NM2 + part * 8);
    *(int4*)(lds + 32768 + sw) = vb;
  }
  __syncthreads();
  f32x4 acc[2][8] = {};
#pragma unroll
  for (int ks = 0; ks < 4; ++ks) {
    const int ar0 = wave * 32 + (lane & 15);
    const int ar1 = ar0 + 16;
    const int koff = ks * 64 + (lane >> 4) * 16;
    bf16x8 a0 = *(const bf16x8*)(lds + ((ar0 * 256 + koff) ^ ((unsigned)(ar0 & 7) << 4)));
    bf16x8 a1 = *(const bf16x8*)(lds + ((ar1 * 256 + koff) ^ ((unsigned)(ar1 & 7) << 4)));
#pragma unroll
    for (int t = 0; t < 8; ++t) {
      const int col = t * 16 + (lane & 15);
      bf16x8 bv = *(const bf16x8*)(lds + 32768 + ((col * 256 + koff) ^ ((unsigned)(col & 7) << 4)));
      acc[0][t] = __builtin_amdgcn_mfma_f32_16x16x32_bf16(a0, bv, acc[0][t], 0, 0, 0);
      acc[1][t] = __builtin_amdgcn_mfma_f32_16x16x32_bf16(a1, bv, acc[1][t], 0, 0, 0);
    }
  }
  // store: t innermost -> per row 8 back-to-back 64B stores (full 512B span, L2 merge)
#pragma unroll
  for (int m = 0; m < 2; ++m) {
#pragma unroll
    for (int j = 0; j < 4; ++j) {
      const int row = r0 + wave * 32 + m * 16 + (lane >> 4) * 4 + j;
#pragma unroll
      for (int t = 0; t < 8; ++t) {
        const int col = n0 + t * 16 + (lane & 15);
        out[row * SEQ + col] = acc[m][t][j];
      }
    }
  }
}

extern "C" void kernel_launch(void* const* d_in, const int* in_sizes, int n_in,
                              void* d_out, int out_size, void* d_ws, size_t ws_size,
                              hipStream_t stream) {
  const float* x  = (const float*)d_in[0];
  const float* wr = (const float*)d_in[1];
  const float* wi = (const float*)d_in[2];
  float* out = (float*)d_out;
  char* ws = (char*)d_ws;
  // ws layout: t1sw 512K | t2t 512K | P (bf16) 2x4M = 8M | Bx 4M   (total ~13.5 MB)
  unsigned short* t1sw = (unsigned short*)(ws);
  unsigned short* t2t  = (unsigned short*)(ws + 524288);
  unsigned short* P    = (unsigned short*)(ws + 1048576);
  unsigned short* Bx   = (unsigned short*)(ws + 1048576 + (size_t)KS * 16384 * NM2 * 2);

  k_tables<<<dim3(1024), dim3(256), 0, stream>>>(t1sw, t2t);
  k_gemm1 <<<dim3(256 * KS), dim3(256), 0, stream>>>(x, t1sw, P);
  k_stage2<<<dim3(256),  dim3(256), 0, stream>>>(P, wr, wi, Bx);
  k_gemm2 <<<dim3(2048), dim3(256), 0, stream>>>(Bx, t2t, out);
}